// Round 4
// baseline (189.358 us; speedup 1.0000x reference)
//
#include <hip/hip_runtime.h>
#include <cstdint>

#define Bsz 2
#define Lsz 2048
#define Dm  512
#define Nst 64
#define Rr  32
#define Ee  160   // r + 2n
#define NCHUNK 32
#define CLEN   64

__device__ __forceinline__ float rdlane(float v, int l) {
    return __int_as_float(__builtin_amdgcn_readlane(__float_as_int(v), l));
}

// ---------------- K0: Wt4[k4][e] = float4(W[e][4k4..4k4+3]) ----------------
__global__ __launch_bounds__(256) void k0_wt(const float* __restrict__ W,
                                             float4* __restrict__ Wt4) {
    int gid = blockIdx.x * 256 + threadIdx.x;   // 20480 total
    int k4 = gid & 127, e = gid >> 7;
    float4 v = *reinterpret_cast<const float4*>(W + (size_t)e * Dm + k4 * 4);
    Wt4[k4 * Ee + e] = v;
}

// ---------------- K1: xdbl = x @ W^T via Wt4; lane = e, rows via s_load ----------------
__global__ __launch_bounds__(192) void k1_xproj(const float* __restrict__ x,
                                                const float4* __restrict__ Wt4,
                                                float* __restrict__ xdbl) {
    const int tid = threadIdx.x;
    const int e = (tid < Ee) ? tid : (Ee - 1);
    const int row0 = blockIdx.x * 8;
    float acc[8] = {0.f, 0.f, 0.f, 0.f, 0.f, 0.f, 0.f, 0.f};
    #pragma unroll 2
    for (int k4 = 0; k4 < 128; ++k4) {
        const float4 wv = Wt4[k4 * Ee + e];
        #pragma unroll
        for (int r = 0; r < 8; ++r) {
            const float4 xv = *reinterpret_cast<const float4*>(
                x + (size_t)(row0 + r) * Dm + k4 * 4);   // uniform -> s_load
            acc[r] = fmaf(xv.x, wv.x, acc[r]);
            acc[r] = fmaf(xv.y, wv.y, acc[r]);
            acc[r] = fmaf(xv.z, wv.z, acc[r]);
            acc[r] = fmaf(xv.w, wv.w, acc[r]);
        }
    }
    if (tid < Ee) {
        #pragma unroll
        for (int r = 0; r < 8; ++r)
            xdbl[(size_t)(row0 + r) * Ee + tid] = acc[r];
    }
}

// ------- K2: delta = softplus(delta_r @ W_dt^T + b_dt); store delta_t, du_t (b,d,l);
//             also sumdl[chan][chunk] = sum of delta over the 64-step chunk -------
__global__ __launch_bounds__(256) void k2_delta(const float* __restrict__ xdbl,
                                                const float* __restrict__ x,
                                                const float* __restrict__ Wdt,
                                                const float* __restrict__ bdt,
                                                float* __restrict__ delta_t,
                                                float* __restrict__ du_t,
                                                float* __restrict__ sumdl) {
    __shared__ float dr[64][33];
    __shared__ float wd[64][32];
    __shared__ float pt[64][65];
    const int tid = threadIdx.x;
    const int lt = blockIdx.x & 31;
    const int dt = (blockIdx.x >> 5) & 7;
    const int b  = blockIdx.x >> 8;
    const int l0 = lt * 64, d0 = dt * 64;

    for (int i = tid; i < 512; i += 256) {
        int l = i >> 3, j4 = i & 7;
        const float4 v = *reinterpret_cast<const float4*>(
            xdbl + (size_t)(b * Lsz + l0 + l) * Ee + j4 * 4);
        dr[l][j4 * 4 + 0] = v.x; dr[l][j4 * 4 + 1] = v.y;
        dr[l][j4 * 4 + 2] = v.z; dr[l][j4 * 4 + 3] = v.w;
    }
    for (int i = tid; i < 512; i += 256) {
        int dd = i >> 3, j4 = i & 7;
        *reinterpret_cast<float4*>(&wd[dd][j4 * 4]) =
            *reinterpret_cast<const float4*>(Wdt + (size_t)(d0 + dd) * Rr + j4 * 4);
    }
    __syncthreads();

    const int w = tid >> 6, lane = tid & 63;
    float drr[32];
    #pragma unroll
    for (int j = 0; j < 32; ++j) drr[j] = dr[lane][j];

    float xv[16];
    {
        const float* xp = x + (size_t)(b * Lsz + l0 + lane) * Dm + d0 + w * 16;
        #pragma unroll
        for (int q = 0; q < 4; ++q) {
            float4 v = reinterpret_cast<const float4*>(xp)[q];
            xv[q*4] = v.x; xv[q*4+1] = v.y; xv[q*4+2] = v.z; xv[q*4+3] = v.w;
        }
    }

    float dl[16];
    #pragma unroll
    for (int i = 0; i < 16; ++i) {
        int dd = w * 16 + i;
        float z = bdt[d0 + dd];
        const float4* wr = reinterpret_cast<const float4*>(&wd[dd][0]);
        #pragma unroll
        for (int j4 = 0; j4 < 8; ++j4) {
            float4 wv = wr[j4];
            z = fmaf(drr[j4*4+0], wv.x, z);
            z = fmaf(drr[j4*4+1], wv.y, z);
            z = fmaf(drr[j4*4+2], wv.z, z);
            z = fmaf(drr[j4*4+3], wv.w, z);
        }
        dl[i] = (z > 20.f) ? z : log1pf(expf(z));
    }

    #pragma unroll
    for (int i = 0; i < 16; ++i) pt[w * 16 + i][lane] = dl[i];
    __syncthreads();
    for (int i = tid; i < 4096; i += 256) {
        int dd = i >> 6, ll = i & 63;
        delta_t[((size_t)(b * Dm + d0 + dd)) * Lsz + l0 + ll] = pt[dd][ll];
    }
    if (tid < 64) {                       // chunk-sum of delta for channel d0+tid
        float s = 0.f;
        #pragma unroll 16
        for (int q = 0; q < 64; ++q) s += pt[tid][q];
        sumdl[(size_t)(b * Dm + d0 + tid) * NCHUNK + lt] = s;
    }
    __syncthreads();
    #pragma unroll
    for (int i = 0; i < 16; ++i) pt[w * 16 + i][lane] = dl[i] * xv[i];
    __syncthreads();
    for (int i = tid; i < 4096; i += 256) {
        int dd = i >> 6, ll = i & 63;
        du_t[((size_t)(b * Dm + d0 + dd)) * Lsz + l0 + ll] = pt[dd][ll];
    }
}

// ---------------- K3a: local chunk scans (h0 = 0) -> hf; 8 chans/wave,
//                  delta/du broadcast from registers via v_readlane ----------------
__global__ __launch_bounds__(256) void k3a(const float* __restrict__ delta_t,
                                           const float* __restrict__ du_t,
                                           const float* __restrict__ xdbl,
                                           const float* __restrict__ Alog,
                                           float* __restrict__ hf) {
    __shared__ float Bs[64][64];           // 16 KB, shared by 32 chans
    const int tid = threadIdx.x;
    const int w = __builtin_amdgcn_readfirstlane(tid >> 6);
    const int lane = tid & 63;
    const int c   = blockIdx.x & 31;       // chunk
    const int grp = blockIdx.x >> 5;       // 0..31
    const int chan0 = grp * 32 + w * 8;
    const int b = chan0 >> 9;
    const int t0 = c * CLEN;
    const float* __restrict__ xb0 = xdbl + ((size_t)b * Lsz + t0) * Ee;
    for (int i = tid; i < 1024; i += 256) {
        int row = i >> 4, q = i & 15;
        float4 v = *reinterpret_cast<const float4*>(xb0 + row * Ee + Rr + q * 4);
        *reinterpret_cast<float4*>(&Bs[row][q * 4]) = v;
    }
    float A2[8], h[8], dreg[8], ureg[8];
    #pragma unroll
    for (int ch = 0; ch < 8; ++ch) {
        const int cc = chan0 + ch;
        A2[ch] = -expf(Alog[(size_t)(cc & 511) * Nst + lane]) * 1.44269504f;
        dreg[ch] = delta_t[(size_t)cc * Lsz + t0 + lane];   // 64 steps, per-lane
        ureg[ch] = du_t   [(size_t)cc * Lsz + t0 + lane];
        h[ch] = 0.f;
    }
    __syncthreads();
    #pragma unroll 8
    for (int j = 0; j < CLEN; ++j) {
        float Bv = Bs[j][lane];
        #pragma unroll
        for (int ch = 0; ch < 8; ++ch) {
            float sd = rdlane(dreg[ch], j);
            float su = rdlane(ureg[ch], j);
            h[ch] = fmaf(exp2f(sd * A2[ch]), h[ch], su * Bv);
        }
    }
    #pragma unroll
    for (int ch = 0; ch < 8; ++ch)
        hf[((size_t)(chan0 + ch) * NCHUNK + c) * Nst + lane] = h[ch];
}

// ---------------- K3b: sequential fix-up over chunks; hf <- h0 (in place),
//                  software-pipelined hf prefetch ----------------
__global__ __launch_bounds__(256) void k3b(const float* __restrict__ Alog,
                                           const float* __restrict__ sumdl,
                                           float* __restrict__ hf) {
    const int tid = threadIdx.x;
    const int w = tid >> 6, lane = tid & 63;
    const int chan = blockIdx.x * 4 + w;
    const int d = chan & 511;
    const float A2 = -expf(Alog[(size_t)d * Nst + lane]) * 1.44269504f;
    const float sv = sumdl[chan * NCHUNK + (lane & 31)];
    const size_t base = (size_t)chan * NCHUNK * Nst + lane;
    float hv[8], nx[8];
    #pragma unroll
    for (int i = 0; i < 8; ++i) hv[i] = hf[base + i * Nst];
    float h0 = 0.f;
    for (int g = 0; g < 4; ++g) {
        if (g < 3) {
            #pragma unroll
            for (int i = 0; i < 8; ++i) nx[i] = hf[base + ((g + 1) * 8 + i) * Nst];
        }
        #pragma unroll
        for (int i = 0; i < 8; ++i) {
            const int c = g * 8 + i;
            float P = exp2f(A2 * rdlane(sv, c));
            hf[base + c * Nst] = h0;              // h0 entering chunk c
            h0 = fmaf(P, h0, hv[i]);
        }
        #pragma unroll
        for (int i = 0; i < 8; ++i) hv[i] = nx[i];
    }
}

// ---------------- K3c: chunk scans from h0, emit y (b,d,l); 8 chans/wave,
//                  register-broadcast delta/du, split BC staging ----------------
__global__ __launch_bounds__(256) void k3c(const float* __restrict__ delta_t,
                                           const float* __restrict__ du_t,
                                           const float* __restrict__ xdbl,
                                           const float* __restrict__ Alog,
                                           const float* __restrict__ h0s,
                                           float* __restrict__ y_t) {
    __shared__ float BC[32][128];          // half-chunk B | C (16 KB)
    __shared__ float part[4][16][65];      // per-wave: 16 rows = 8 chans x 2 steps
    __shared__ float ystage[4][8][66];     // per-wave y staging
    const int tid = threadIdx.x;
    const int w = __builtin_amdgcn_readfirstlane(tid >> 6);
    const int lane = tid & 63;
    const int c   = blockIdx.x & 31;
    const int grp = blockIdx.x >> 5;
    const int chan0 = grp * 32 + w * 8;
    const int b = chan0 >> 9;
    const int t0 = c * CLEN;
    const float* __restrict__ xb0 = xdbl + ((size_t)b * Lsz + t0) * Ee;

    float A2[8], h[8], dreg[8], ureg[8];
    #pragma unroll
    for (int ch = 0; ch < 8; ++ch) {
        const int cc = chan0 + ch;
        A2[ch] = -expf(Alog[(size_t)(cc & 511) * Nst + lane]) * 1.44269504f;
        dreg[ch] = delta_t[(size_t)cc * Lsz + t0 + lane];
        ureg[ch] = du_t   [(size_t)cc * Lsz + t0 + lane];
        h[ch] = h0s[((size_t)cc * NCHUNK + c) * Nst + lane];
    }
    const int r = lane & 15, seg = lane >> 4;

    #pragma unroll
    for (int half = 0; half < 2; ++half) {
        if (half) __syncthreads();                       // protect BC overwrite
        for (int i = tid; i < 1024; i += 256) {          // stage 32 rows of B|C
            int row = i >> 5, q4 = i & 31;
            float4 v = *reinterpret_cast<const float4*>(
                xb0 + (half * 32 + row) * Ee + Rr + q4 * 4);
            *reinterpret_cast<float4*>(&BC[row][q4 * 4]) = v;
        }
        __syncthreads();
        #pragma unroll 4
        for (int g2 = 0; g2 < 16; ++g2) {
            #pragma unroll
            for (int jj = 0; jj < 2; ++jj) {
                const int tt = g2 * 2 + jj;              // 0..31 within half
                const int t  = half * 32 + tt;           // 0..63 (readlane idx)
                float Bv = BC[tt][lane];
                float Cv = BC[tt][64 + lane];
                #pragma unroll
                for (int ch = 0; ch < 8; ++ch) {
                    float sd = rdlane(dreg[ch], t);
                    float su = rdlane(ureg[ch], t);
                    h[ch] = fmaf(exp2f(sd * A2[ch]), h[ch], su * Bv);
                    part[w][ch * 2 + jj][lane] = h[ch] * Cv;
                }
            }
            float v = 0.f;
            #pragma unroll
            for (int q = 0; q < 16; ++q) v += part[w][r][seg * 16 + q];
            v += __shfl_xor(v, 16);
            v += __shfl_xor(v, 32);
            if (lane < 16) ystage[w][r >> 1][half * 32 + g2 * 2 + (r & 1)] = v;
        }
    }
    #pragma unroll
    for (int ch = 0; ch < 8; ++ch)
        y_t[(size_t)(chan0 + ch) * Lsz + t0 + lane] = ystage[w][ch][lane];
}

// ---------------- K4: out(b,l,d) = y_t(b,d,l)^T + x * D ----------------
__global__ __launch_bounds__(256) void k4_out(const float* __restrict__ y_t,
                                              const float* __restrict__ x,
                                              const float* __restrict__ Dv,
                                              float* __restrict__ out) {
    __shared__ float tl[64][65];
    const int tid = threadIdx.x;
    const int lt = blockIdx.x & 31;
    const int dt = (blockIdx.x >> 5) & 7;
    const int b  = blockIdx.x >> 8;
    const int l0 = lt * 64, d0 = dt * 64;
    for (int i = tid; i < 4096; i += 256) {
        int dd = i >> 6, ll = i & 63;
        tl[dd][ll] = y_t[((size_t)(b * Dm + d0 + dd)) * Lsz + l0 + ll];
    }
    __syncthreads();
    for (int i = tid; i < 4096; i += 256) {
        int ll = i >> 6, dd = i & 63;
        size_t gi = ((size_t)(b * Lsz + l0 + ll)) * Dm + d0 + dd;
        out[gi] = tl[dd][ll] + x[gi] * Dv[d0 + dd];
    }
}

extern "C" void kernel_launch(void* const* d_in, const int* in_sizes, int n_in,
                              void* d_out, int out_size, void* d_ws, size_t ws_size,
                              hipStream_t stream) {
    const float* x    = (const float*)d_in[0];
    const float* Wxp  = (const float*)d_in[1];
    const float* Wdt  = (const float*)d_in[2];
    const float* bdt  = (const float*)d_in[3];
    const float* Alog = (const float*)d_in[4];
    const float* Dv   = (const float*)d_in[5];
    float* out = (float*)d_out;

    float* ws = (float*)d_ws;
    float*  xdbl    = ws;                                   // 655,360
    float4* Wt4     = (float4*)(ws + 655360);               // 81,920 floats
    float*  delta_t = ws + 737280;                          // 2,097,152
    float*  du_t    = ws + 2834432;                         // 2,097,152
    float*  y_t     = ws + 4931584;                         // 2,097,152
    float*  hf      = ws + 7028736;                         // 2,097,152
    float*  sumdl   = ws + 9125888;                         // 32,768

    hipLaunchKernelGGL(k0_wt,    dim3(80),   dim3(256), 0, stream, Wxp, Wt4);
    hipLaunchKernelGGL(k1_xproj, dim3(512),  dim3(192), 0, stream, x, Wt4, xdbl);
    hipLaunchKernelGGL(k2_delta, dim3(512),  dim3(256), 0, stream, xdbl, x, Wdt, bdt, delta_t, du_t, sumdl);
    hipLaunchKernelGGL(k3a,      dim3(1024), dim3(256), 0, stream, delta_t, du_t, xdbl, Alog, hf);
    hipLaunchKernelGGL(k3b,      dim3(256),  dim3(256), 0, stream, Alog, sumdl, hf);
    hipLaunchKernelGGL(k3c,      dim3(1024), dim3(256), 0, stream, delta_t, du_t, xdbl, Alog, hf, y_t);
    hipLaunchKernelGGL(k4_out,   dim3(512),  dim3(256), 0, stream, y_t, x, Dv, out);
}

// Round 6
// 149.303 us; speedup vs baseline: 1.2683x; 1.2683x over previous
//
#include <hip/hip_runtime.h>
#include <cstdint>

#define Bsz 2
#define Lsz 2048
#define Dm  512
#define Nst 64
#define Rr  32
#define Ee  160   // r + 2n
#define NCHUNK 32
#define CLEN   64
#define L2E 1.44269504f
#define LN2 0.69314718f

__device__ __forceinline__ float rdlane(float v, int l) {
    return __int_as_float(__builtin_amdgcn_readlane(__float_as_int(v), l));
}
// raw v_exp_f32 / v_log_f32 (log2). All hot exp args are <= 0.
__device__ __forceinline__ float fexp2(float x) { return __builtin_amdgcn_exp2f(x); }
__device__ __forceinline__ float flog2(float x) { return __builtin_amdgcn_logf(x); }

// ---------------- K0: Wt4[k4][e] = float4(W[e][4k4..4k4+3]) ----------------
__global__ __launch_bounds__(256) void k0_wt(const float* __restrict__ W,
                                             float4* __restrict__ Wt4) {
    int gid = blockIdx.x * 256 + threadIdx.x;   // 20480 total
    int k4 = gid & 127, e = gid >> 7;
    float4 v = *reinterpret_cast<const float4*>(W + (size_t)e * Dm + k4 * 4);
    Wt4[k4 * Ee + e] = v;
}

// ---------------- K1: xdbl = x @ W^T via Wt4; lane = e, rows via s_load ----------------
__global__ __launch_bounds__(192) void k1_xproj(const float* __restrict__ x,
                                                const float4* __restrict__ Wt4,
                                                float* __restrict__ xdbl) {
    const int tid = threadIdx.x;
    const int e = (tid < Ee) ? tid : (Ee - 1);
    const int row0 = blockIdx.x * 8;
    float acc[8] = {0.f, 0.f, 0.f, 0.f, 0.f, 0.f, 0.f, 0.f};
    #pragma unroll 2
    for (int k4 = 0; k4 < 128; ++k4) {
        const float4 wv = Wt4[k4 * Ee + e];
        #pragma unroll
        for (int r = 0; r < 8; ++r) {
            const float4 xv = *reinterpret_cast<const float4*>(
                x + (size_t)(row0 + r) * Dm + k4 * 4);   // uniform -> s_load
            acc[r] = fmaf(xv.x, wv.x, acc[r]);
            acc[r] = fmaf(xv.y, wv.y, acc[r]);
            acc[r] = fmaf(xv.z, wv.z, acc[r]);
            acc[r] = fmaf(xv.w, wv.w, acc[r]);
        }
    }
    if (tid < Ee) {
        #pragma unroll
        for (int r = 0; r < 8; ++r)
            xdbl[(size_t)(row0 + r) * Ee + tid] = acc[r];
    }
}

// ------- K2: delta = softplus(delta_r @ W_dt^T + b_dt); store delta_t, du_t (b,d,l);
//             also sumdl[chan][chunk] = sum of delta over the 64-step chunk -------
__global__ __launch_bounds__(256) void k2_delta(const float* __restrict__ xdbl,
                                                const float* __restrict__ x,
                                                const float* __restrict__ Wdt,
                                                const float* __restrict__ bdt,
                                                float* __restrict__ delta_t,
                                                float* __restrict__ du_t,
                                                float* __restrict__ sumdl) {
    __shared__ float dr[64][33];
    __shared__ float wd[64][32];
    __shared__ float pt[64][65];
    const int tid = threadIdx.x;
    const int lt = blockIdx.x & 31;
    const int dt = (blockIdx.x >> 5) & 7;
    const int b  = blockIdx.x >> 8;
    const int l0 = lt * 64, d0 = dt * 64;

    for (int i = tid; i < 512; i += 256) {
        int l = i >> 3, j4 = i & 7;
        const float4 v = *reinterpret_cast<const float4*>(
            xdbl + (size_t)(b * Lsz + l0 + l) * Ee + j4 * 4);
        dr[l][j4 * 4 + 0] = v.x; dr[l][j4 * 4 + 1] = v.y;
        dr[l][j4 * 4 + 2] = v.z; dr[l][j4 * 4 + 3] = v.w;
    }
    for (int i = tid; i < 512; i += 256) {
        int dd = i >> 3, j4 = i & 7;
        *reinterpret_cast<float4*>(&wd[dd][j4 * 4]) =
            *reinterpret_cast<const float4*>(Wdt + (size_t)(d0 + dd) * Rr + j4 * 4);
    }
    __syncthreads();

    const int w = tid >> 6, lane = tid & 63;
    float drr[32];
    #pragma unroll
    for (int j = 0; j < 32; ++j) drr[j] = dr[lane][j];

    float xv[16];
    {
        const float* xp = x + (size_t)(b * Lsz + l0 + lane) * Dm + d0 + w * 16;
        #pragma unroll
        for (int q = 0; q < 4; ++q) {
            float4 v = reinterpret_cast<const float4*>(xp)[q];
            xv[q*4] = v.x; xv[q*4+1] = v.y; xv[q*4+2] = v.z; xv[q*4+3] = v.w;
        }
    }

    float dl[16];
    #pragma unroll
    for (int i = 0; i < 16; ++i) {
        int dd = w * 16 + i;
        float z = bdt[d0 + dd];
        const float4* wr = reinterpret_cast<const float4*>(&wd[dd][0]);
        #pragma unroll
        for (int j4 = 0; j4 < 8; ++j4) {
            float4 wv = wr[j4];
            z = fmaf(drr[j4*4+0], wv.x, z);
            z = fmaf(drr[j4*4+1], wv.y, z);
            z = fmaf(drr[j4*4+2], wv.z, z);
            z = fmaf(drr[j4*4+3], wv.w, z);
        }
        // softplus(z) = max(z,0) + ln(1 + exp(-|z|)), raw exp2/log2 path
        float t = fexp2(-fabsf(z) * L2E);
        dl[i] = fmaxf(z, 0.f) + flog2(1.f + t) * LN2;
    }

    #pragma unroll
    for (int i = 0; i < 16; ++i) pt[w * 16 + i][lane] = dl[i];
    __syncthreads();
    for (int i = tid; i < 4096; i += 256) {
        int dd = i >> 6, ll = i & 63;
        delta_t[((size_t)(b * Dm + d0 + dd)) * Lsz + l0 + ll] = pt[dd][ll];
    }
    if (tid < 64) {                       // chunk-sum of delta for channel d0+tid
        float s = 0.f;
        #pragma unroll 16
        for (int q = 0; q < 64; ++q) s += pt[tid][q];
        sumdl[(size_t)(b * Dm + d0 + tid) * NCHUNK + lt] = s;
    }
    __syncthreads();
    #pragma unroll
    for (int i = 0; i < 16; ++i) pt[w * 16 + i][lane] = dl[i] * xv[i];
    __syncthreads();
    for (int i = tid; i < 4096; i += 256) {
        int dd = i >> 6, ll = i & 63;
        du_t[((size_t)(b * Dm + d0 + dd)) * Lsz + l0 + ll] = pt[dd][ll];
    }
}

// ---------------- K3a: local chunk scans (h0 = 0) -> hf; 8 chans/wave ----------------
__global__ __launch_bounds__(256) void k3a(const float* __restrict__ delta_t,
                                           const float* __restrict__ du_t,
                                           const float* __restrict__ xdbl,
                                           const float* __restrict__ Alog,
                                           float* __restrict__ hf) {
    __shared__ float Bs[64][64];           // 16 KB, shared by 32 chans
    const int tid = threadIdx.x;
    const int w = __builtin_amdgcn_readfirstlane(tid >> 6);
    const int lane = tid & 63;
    const int c   = blockIdx.x & 31;       // chunk
    const int grp = blockIdx.x >> 5;       // 0..31
    const int chan0 = grp * 32 + w * 8;
    const int b = chan0 >> 9;
    const int t0 = c * CLEN;
    const float* __restrict__ xb0 = xdbl + ((size_t)b * Lsz + t0) * Ee;
    for (int i = tid; i < 1024; i += 256) {
        int row = i >> 4, q = i & 15;
        float4 v = *reinterpret_cast<const float4*>(xb0 + row * Ee + Rr + q * 4);
        *reinterpret_cast<float4*>(&Bs[row][q * 4]) = v;
    }
    float A2[8], h[8], dreg[8], ureg[8];
    #pragma unroll
    for (int ch = 0; ch < 8; ++ch) {
        const int cc = chan0 + ch;
        A2[ch] = -expf(Alog[(size_t)(cc & 511) * Nst + lane]) * L2E;
        dreg[ch] = delta_t[(size_t)cc * Lsz + t0 + lane];   // 64 steps, per-lane
        ureg[ch] = du_t   [(size_t)cc * Lsz + t0 + lane];
        h[ch] = 0.f;
    }
    __syncthreads();
    #pragma unroll 8
    for (int j = 0; j < CLEN; ++j) {
        float Bv = Bs[j][lane];
        #pragma unroll
        for (int ch = 0; ch < 8; ++ch) {
            float sd = rdlane(dreg[ch], j);
            float su = rdlane(ureg[ch], j);
            h[ch] = fmaf(fexp2(sd * A2[ch]), h[ch], su * Bv);
        }
    }
    #pragma unroll
    for (int ch = 0; ch < 8; ++ch)
        hf[((size_t)(chan0 + ch) * NCHUNK + c) * Nst + lane] = h[ch];
}

// ---------------- K3b: sequential fix-up over chunks; hf <- h0 (in place) ----------------
__global__ __launch_bounds__(256) void k3b(const float* __restrict__ Alog,
                                           const float* __restrict__ sumdl,
                                           float* __restrict__ hf) {
    const int tid = threadIdx.x;
    const int w = tid >> 6, lane = tid & 63;
    const int chan = blockIdx.x * 4 + w;
    const int d = chan & 511;
    const float A2 = -expf(Alog[(size_t)d * Nst + lane]) * L2E;
    const float sv = sumdl[chan * NCHUNK + (lane & 31)];
    const size_t base = (size_t)chan * NCHUNK * Nst + lane;
    float hv[8], nx[8];
    #pragma unroll
    for (int i = 0; i < 8; ++i) hv[i] = hf[base + i * Nst];
    float h0 = 0.f;
    for (int g = 0; g < 4; ++g) {
        if (g < 3) {
            #pragma unroll
            for (int i = 0; i < 8; ++i) nx[i] = hf[base + ((g + 1) * 8 + i) * Nst];
        }
        #pragma unroll
        for (int i = 0; i < 8; ++i) {
            const int c = g * 8 + i;
            float P = fexp2(A2 * rdlane(sv, c));
            hf[base + c * Nst] = h0;              // h0 entering chunk c
            h0 = fmaf(P, h0, hv[i]);
        }
        #pragma unroll
        for (int i = 0; i < 8; ++i) hv[i] = nx[i];
    }
}

// ---------------- K3c: chunk scans from h0, emit y (b,d,l); 8 chans/wave,
//                  round-4 structure (ystage LDS buffer) ----------------
__global__ __launch_bounds__(256) void k3c(const float* __restrict__ delta_t,
                                           const float* __restrict__ du_t,
                                           const float* __restrict__ xdbl,
                                           const float* __restrict__ Alog,
                                           const float* __restrict__ h0s,
                                           float* __restrict__ y_t) {
    __shared__ float BC[32][128];          // half-chunk B | C (16 KB)
    __shared__ float part[4][16][65];      // per-wave: 16 rows = 8 chans x 2 steps
    __shared__ float ystage[4][8][66];     // per-wave y staging
    const int tid = threadIdx.x;
    const int w = __builtin_amdgcn_readfirstlane(tid >> 6);
    const int lane = tid & 63;
    const int c   = blockIdx.x & 31;
    const int grp = blockIdx.x >> 5;
    const int chan0 = grp * 32 + w * 8;
    const int b = chan0 >> 9;
    const int t0 = c * CLEN;
    const float* __restrict__ xb0 = xdbl + ((size_t)b * Lsz + t0) * Ee;

    float A2[8], h[8], dreg[8], ureg[8];
    #pragma unroll
    for (int ch = 0; ch < 8; ++ch) {
        const int cc = chan0 + ch;
        A2[ch] = -expf(Alog[(size_t)(cc & 511) * Nst + lane]) * L2E;
        dreg[ch] = delta_t[(size_t)cc * Lsz + t0 + lane];
        ureg[ch] = du_t   [(size_t)cc * Lsz + t0 + lane];
        h[ch] = h0s[((size_t)cc * NCHUNK + c) * Nst + lane];
    }
    const int r = lane & 15, seg = lane >> 4;

    #pragma unroll
    for (int half = 0; half < 2; ++half) {
        if (half) __syncthreads();                       // protect BC overwrite
        for (int i = tid; i < 1024; i += 256) {          // stage 32 rows of B|C
            int row = i >> 5, q4 = i & 31;
            float4 v = *reinterpret_cast<const float4*>(
                xb0 + (half * 32 + row) * Ee + Rr + q4 * 4);
            *reinterpret_cast<float4*>(&BC[row][q4 * 4]) = v;
        }
        __syncthreads();
        #pragma unroll
        for (int g2 = 0; g2 < 16; ++g2) {
            #pragma unroll
            for (int jj = 0; jj < 2; ++jj) {
                const int tt = g2 * 2 + jj;              // 0..31 within half
                const int t  = half * 32 + tt;           // 0..63 (readlane idx)
                float Bv = BC[tt][lane];
                float Cv = BC[tt][64 + lane];
                #pragma unroll
                for (int ch = 0; ch < 8; ++ch) {
                    float sd = rdlane(dreg[ch], t);
                    float su = rdlane(ureg[ch], t);
                    h[ch] = fmaf(fexp2(sd * A2[ch]), h[ch], su * Bv);
                    part[w][ch * 2 + jj][lane] = h[ch] * Cv;
                }
            }
            float v = 0.f;
            #pragma unroll
            for (int q = 0; q < 16; ++q) v += part[w][r][seg * 16 + q];
            v += __shfl_xor(v, 16);
            v += __shfl_xor(v, 32);
            if (lane < 16) ystage[w][r >> 1][half * 32 + g2 * 2 + (r & 1)] = v;
        }
    }
    #pragma unroll
    for (int ch = 0; ch < 8; ++ch)
        y_t[(size_t)(chan0 + ch) * Lsz + t0 + lane] = ystage[w][ch][lane];
}

// ---------------- K4: out(b,l,d) = y_t(b,d,l)^T + x * D ----------------
__global__ __launch_bounds__(256) void k4_out(const float* __restrict__ y_t,
                                              const float* __restrict__ x,
                                              const float* __restrict__ Dv,
                                              float* __restrict__ out) {
    __shared__ float tl[64][65];
    const int tid = threadIdx.x;
    const int lt = blockIdx.x & 31;
    const int dt = (blockIdx.x >> 5) & 7;
    const int b  = blockIdx.x >> 8;
    const int l0 = lt * 64, d0 = dt * 64;
    for (int i = tid; i < 4096; i += 256) {
        int dd = i >> 6, ll = i & 63;
        tl[dd][ll] = y_t[((size_t)(b * Dm + d0 + dd)) * Lsz + l0 + ll];
    }
    __syncthreads();
    for (int i = tid; i < 4096; i += 256) {
        int ll = i >> 6, dd = i & 63;
        size_t gi = ((size_t)(b * Lsz + l0 + ll)) * Dm + d0 + dd;
        out[gi] = tl[dd][ll] + x[gi] * Dv[d0 + dd];
    }
}

extern "C" void kernel_launch(void* const* d_in, const int* in_sizes, int n_in,
                              void* d_out, int out_size, void* d_ws, size_t ws_size,
                              hipStream_t stream) {
    const float* x    = (const float*)d_in[0];
    const float* Wxp  = (const float*)d_in[1];
    const float* Wdt  = (const float*)d_in[2];
    const float* bdt  = (const float*)d_in[3];
    const float* Alog = (const float*)d_in[4];
    const float* Dv   = (const float*)d_in[5];
    float* out = (float*)d_out;

    float* ws = (float*)d_ws;
    float*  xdbl    = ws;                                   // 655,360
    float4* Wt4     = (float4*)(ws + 655360);               // 81,920 floats
    float*  delta_t = ws + 737280;                          // 2,097,152
    float*  du_t    = ws + 2834432;                         // 2,097,152
    float*  y_t     = ws + 4931584;                         // 2,097,152
    float*  hf      = ws + 7028736;                         // 2,097,152
    float*  sumdl   = ws + 9125888;                         // 32,768

    hipLaunchKernelGGL(k0_wt,    dim3(80),   dim3(256), 0, stream, Wxp, Wt4);
    hipLaunchKernelGGL(k1_xproj, dim3(512),  dim3(192), 0, stream, x, Wt4, xdbl);
    hipLaunchKernelGGL(k2_delta, dim3(512),  dim3(256), 0, stream, xdbl, x, Wdt, bdt, delta_t, du_t, sumdl);
    hipLaunchKernelGGL(k3a,      dim3(1024), dim3(256), 0, stream, delta_t, du_t, xdbl, Alog, hf);
    hipLaunchKernelGGL(k3b,      dim3(256),  dim3(256), 0, stream, Alog, sumdl, hf);
    hipLaunchKernelGGL(k3c,      dim3(1024), dim3(256), 0, stream, delta_t, du_t, xdbl, Alog, hf, y_t);
    hipLaunchKernelGGL(k4_out,   dim3(512),  dim3(256), 0, stream, y_t, x, Dv, out);
}